// Round 2
// baseline (364.004 us; speedup 1.0000x reference)
//
#include <hip/hip_runtime.h>
#include <stdint.h>

// ---------------------------------------------------------------------------
// BondPoolingLayer: out[e] = MLP(cat(h[src],h[dst])) + MLP(cat(h[dst],h[src]))
// MLP: 256 ->(W1,b1,relu) 128 ->(W2,b2,relu) 128 ->(W3,b3) 2
//
// P[n,0:128] = h[n] @ W1_top ; P[n,128:256] = h[n] @ W1_bot + b1   (bf16)
//   fwd layer1 preact = P[s,0:128] + P[d,128:256]
//   rev layer1 preact = P[d,0:128] + P[s,128:256]
//
// R2: both hot kernels are LDS-free and barrier-free.
//  - node_proj: A=W1t (from L1/L2), B=h^T (fp32 global + reg cvt). D cols =
//    nodes, D rows = features -> 4 acc regs are 4 consecutive features ->
//    packed 8B stores, no transpose.
//  - edge_mlp: layer-1 relu-add is elementwise in k, so A-fragments are built
//    in registers from two 16B gathers of P; W2 B-frags straight from L2.
// ---------------------------------------------------------------------------

typedef __attribute__((ext_vector_type(8))) short bf16x8;
typedef __attribute__((ext_vector_type(4))) float f32x4;

__device__ __forceinline__ unsigned short f2bf(float f) {
    union { float f; unsigned u; } v; v.f = f;
    unsigned u = v.u;
    unsigned r = u + 0x7FFFu + ((u >> 16) & 1u);   // RNE
    return (unsigned short)(r >> 16);
}
__device__ __forceinline__ float bf2f(unsigned u16) {
    union { unsigned u; float f; } v; v.u = u16 << 16;
    return v.f;
}

// 8 consecutive fp32 -> bf16x8 fragment
__device__ __forceinline__ bf16x8 cvt8(const float* p) {
    float4 x = *(const float4*)p;
    float4 y = *(const float4*)(p + 4);
    union { bf16x8 v; unsigned short s[8]; } R;
    R.s[0] = f2bf(x.x); R.s[1] = f2bf(x.y); R.s[2] = f2bf(x.z); R.s[3] = f2bf(x.w);
    R.s[4] = f2bf(y.x); R.s[5] = f2bf(y.y); R.s[6] = f2bf(y.z); R.s[7] = f2bf(y.w);
    return R.v;
}

// elementwise relu(a+b) over 8 bf16 pairs, repacked to bf16x8
__device__ __forceinline__ bf16x8 addrelu8(uint4 a, uint4 b) {
    union { uint4 v; unsigned u[4]; } A, B;
    A.v = a; B.v = b;
    union { bf16x8 v; unsigned short s[8]; } R;
#pragma unroll
    for (int i = 0; i < 4; ++i) {
        float a0 = bf2f(A.u[i] & 0xFFFFu), a1 = bf2f(A.u[i] >> 16);
        float b0 = bf2f(B.u[i] & 0xFFFFu), b1 = bf2f(B.u[i] >> 16);
        R.s[2 * i]     = f2bf(fmaxf(a0 + b0, 0.f));
        R.s[2 * i + 1] = f2bf(fmaxf(a1 + b1, 0.f));
    }
    return R.v;
}

// ---------------------------------------------------------------------------
// Kernel 0: weight prep (bf16 transposes).
// W1t[j][k] (j in [0,256), k in [0,128)) = W1[k][j] (j<128) | W1[k+128][j-128]
// W2t[n][k] = W2[k][n]
// ---------------------------------------------------------------------------
__global__ void prep_weights(const float* __restrict__ W1,
                             const float* __restrict__ W2,
                             unsigned short* __restrict__ W1t,
                             unsigned short* __restrict__ W2t) {
    int idx = blockIdx.x * 256 + threadIdx.x;
    if (idx < 256 * 128) {
        int j = idx >> 7, k = idx & 127;
        float v = (j < 128) ? W1[k * 128 + j] : W1[(k + 128) * 128 + (j - 128)];
        W1t[idx] = f2bf(v);
    } else {
        int i2 = idx - 256 * 128;
        if (i2 < 128 * 128) {
            int n = i2 >> 7, k = i2 & 127;
            W2t[i2] = f2bf(W2[k * 128 + n]);
        }
    }
}

// ---------------------------------------------------------------------------
// Kernel A: node projection. One wave = 16 nodes, all 256 output features.
// D = W1cat (256x128, A-op) x h^T (128x16, B-op).  No LDS, no barriers.
// ---------------------------------------------------------------------------
__global__ __launch_bounds__(256) void node_proj(
    const float* __restrict__ h, const unsigned short* __restrict__ W1t,
    const float* __restrict__ b1, unsigned short* __restrict__ P, int nodes) {
    int t = threadIdx.x;
    int lane = t & 63;
    int w = t >> 6;
    int ml = lane & 15, quad = lane >> 4;
    int nb = blockIdx.x * 64 + w * 16;

    int node = nb + ml;
    int nodeL = (node < nodes) ? node : (nodes - 1);
    const float* hrow = h + (size_t)nodeL * 128;

    f32x4 acc[16] = {};
#pragma unroll
    for (int kk = 0; kk < 4; ++kk) {
        int ko = kk * 32 + quad * 8;
        bf16x8 bfrag = cvt8(hrow + ko);   // B[k][n=ml] = h[node][k], 8 k's
#pragma unroll
        for (int ct = 0; ct < 16; ++ct) {
            bf16x8 afrag = *(const bf16x8*)(W1t + (size_t)(ct * 16 + ml) * 128 + ko);
            acc[ct] = __builtin_amdgcn_mfma_f32_16x16x32_bf16(afrag, bfrag, acc[ct], 0, 0, 0);
        }
    }

    // epilogue: lane ml owns node nb+ml; rows (features) = ct*16 + quad*4 + reg
    if (node < nodes) {
        unsigned short* prow = P + (size_t)node * 256;
#pragma unroll
        for (int ct = 0; ct < 16; ++ct) {
            int fbase = ct * 16 + quad * 4;
            float v0 = acc[ct][0], v1 = acc[ct][1], v2 = acc[ct][2], v3 = acc[ct][3];
            if (fbase >= 128) {
                float4 bv = *(const float4*)(b1 + (fbase - 128));
                v0 += bv.x; v1 += bv.y; v2 += bv.z; v3 += bv.w;
            }
            uint2 o;
            o.x = (unsigned)f2bf(v0) | ((unsigned)f2bf(v1) << 16);
            o.y = (unsigned)f2bf(v2) | ((unsigned)f2bf(v3) << 16);
            *(uint2*)(prow + fbase) = o;
        }
    }
}

// ---------------------------------------------------------------------------
// Kernel B: per-edge MLP. One wave = 16 edges x {fwd,rev}. No LDS, no barriers.
// A-frags built in-register from P gathers; B = W2t from L2; layer-3 (128->2)
// folded into epilogue via 16-lane butterfly.
// ---------------------------------------------------------------------------
__global__ __launch_bounds__(256) void edge_mlp(
    const unsigned short* __restrict__ P, const int* __restrict__ src,
    const int* __restrict__ dst, const unsigned short* __restrict__ W2t,
    const float* __restrict__ b2, const float* __restrict__ W3,
    const float* __restrict__ b3, float* __restrict__ out, int E) {
    int t = threadIdx.x;
    int lane = t & 63;
    int w = t >> 6;
    int ml = lane & 15, quad = lane >> 4;
    int eb = blockIdx.x * 64 + w * 16;

    int e = eb + ml;
    int ec = (e < E) ? e : (E - 1);
    int si = src[ec], di = dst[ec];
    const unsigned short* Ps = P + (size_t)si * 256;
    const unsigned short* Pd = P + (size_t)di * 256;

    f32x4 acc[2][8] = {};
#pragma unroll
    for (int kk = 0; kk < 4; ++kk) {
        int ko = kk * 32 + quad * 8;
        uint4 s_lo = *(const uint4*)(Ps + ko);
        uint4 s_hi = *(const uint4*)(Ps + 128 + ko);
        uint4 d_lo = *(const uint4*)(Pd + ko);
        uint4 d_hi = *(const uint4*)(Pd + 128 + ko);
        bf16x8 afw = addrelu8(s_lo, d_hi);   // fwd: relu(P[s,k] + P[d,128+k])
        bf16x8 arv = addrelu8(d_lo, s_hi);   // rev: relu(P[d,k] + P[s,128+k])
#pragma unroll
        for (int ct = 0; ct < 8; ++ct) {
            bf16x8 bfrag = *(const bf16x8*)(W2t + (size_t)(ct * 16 + ml) * 128 + ko);
            acc[0][ct] = __builtin_amdgcn_mfma_f32_16x16x32_bf16(afw, bfrag, acc[0][ct], 0, 0, 0);
            acc[1][ct] = __builtin_amdgcn_mfma_f32_16x16x32_bf16(arv, bfrag, acc[1][ct], 0, 0, 0);
        }
    }

    // epilogue: +b2, relu, dot W3 columns, butterfly over the 16 feature lanes
    float w30[8], w31[8], b2v[8];
#pragma unroll
    for (int ct = 0; ct < 8; ++ct) {
        int c = ct * 16 + ml;
        w30[ct] = W3[c * 2 + 0];
        w31[ct] = W3[c * 2 + 1];
        b2v[ct] = b2[c];
    }
    float p0[2][4], p1[2][4];
#pragma unroll
    for (int rt = 0; rt < 2; ++rt)
#pragma unroll
        for (int reg = 0; reg < 4; ++reg) { p0[rt][reg] = 0.f; p1[rt][reg] = 0.f; }
#pragma unroll
    for (int rt = 0; rt < 2; ++rt)
#pragma unroll
        for (int ct = 0; ct < 8; ++ct)
#pragma unroll
            for (int reg = 0; reg < 4; ++reg) {
                float h2 = fmaxf(acc[rt][ct][reg] + b2v[ct], 0.f);
                p0[rt][reg] += h2 * w30[ct];
                p1[rt][reg] += h2 * w31[ct];
            }
#pragma unroll
    for (int m = 1; m < 16; m <<= 1) {
#pragma unroll
        for (int rt = 0; rt < 2; ++rt)
#pragma unroll
            for (int reg = 0; reg < 4; ++reg) {
                p0[rt][reg] += __shfl_xor(p0[rt][reg], m);
                p1[rt][reg] += __shfl_xor(p1[rt][reg], m);
            }
    }

    // lane ml==0 writes component 0, ml==1 writes component 1
    if (ml < 2) {
        float bb = 2.f * b3[ml];
#pragma unroll
        for (int reg = 0; reg < 4; ++reg) {
            int ee = eb + quad * 4 + reg;
            if (ee < E) {
                float v = (ml == 0) ? (p0[0][reg] + p0[1][reg])
                                    : (p1[0][reg] + p1[1][reg]);
                out[(size_t)ee * 2 + ml] = v + bb;
            }
        }
    }
}

// ---------------------------------------------------------------------------
extern "C" void kernel_launch(void* const* d_in, const int* in_sizes, int n_in,
                              void* d_out, int out_size, void* d_ws, size_t ws_size,
                              hipStream_t stream) {
    (void)n_in; (void)out_size; (void)ws_size;
    const float* h  = (const float*)d_in[0];
    const int*   sr = (const int*)d_in[1];
    const int*   ds = (const int*)d_in[2];
    const float* W1 = (const float*)d_in[3];
    const float* b1 = (const float*)d_in[4];
    const float* W2 = (const float*)d_in[5];
    const float* b2 = (const float*)d_in[6];
    const float* W3 = (const float*)d_in[7];
    const float* b3 = (const float*)d_in[8];
    float* out = (float*)d_out;

    int nodes = in_sizes[0] / 128;
    int E = in_sizes[1];

    unsigned short* W1t = (unsigned short*)d_ws;          // 256*128
    unsigned short* W2t = W1t + 256 * 128;                // 128*128
    unsigned short* P   = W2t + 128 * 128;                // nodes*256

    prep_weights<<<(256 * 128 + 128 * 128 + 255) / 256, 256, 0, stream>>>(W1, W2, W1t, W2t);

    int ntiles = (nodes + 63) / 64;
    node_proj<<<ntiles, 256, 0, stream>>>(h, W1t, b1, P, nodes);

    int etiles = (E + 63) / 64;
    edge_mlp<<<etiles, 256, 0, stream>>>(P, sr, ds, W2t, b2, W3, b3, out, E);
}

// Round 3
// 249.024 us; speedup vs baseline: 1.4617x; 1.4617x over previous
//
#include <hip/hip_runtime.h>
#include <hip/hip_bf16.h>
#include <stdint.h>

// ---------------------------------------------------------------------------
// BondPoolingLayer: out[e] = MLP(cat(h[src],h[dst])) + MLP(cat(h[dst],h[src]))
// MLP: 256 ->(W1,b1,relu) 128 ->(W2,b2,relu) 128 ->(W3,b3) 2
//
// P[n,0:128] = h[n] @ W1_top ; P[n,128:256] = h[n] @ W1_bot + b1   (bf16)
//   fwd layer1 preact = P[s,0:128] + P[d,128:256]
//   rev layer1 preact = P[d,0:128] + P[s,128:256]
//
// R3: weights persistent in LDS (staged once per block, one barrier, XOR
// swizzle -> every ds_read_b128 is perfectly bank-balanced); streaming
// operand (h rows / P gathers) built in registers; outputs packed.
//  - node_proj: A=W1s(LDS), B=h^T (fp32 global, prefetched, cvt in regs).
//    wave = 32 nodes x 256 features. D rows=features -> 8B packed stores.
//  - edge_mlp: A=W2s(LDS), B=relu-add of P gathers (all 16 loads prefetched).
//    wave = 16 edges x {fwd,rev}; layer-3 folded via 16-lane butterfly.
// ---------------------------------------------------------------------------

typedef __attribute__((ext_vector_type(8))) short bf16x8;
typedef __attribute__((ext_vector_type(4))) float f32x4;

__device__ __forceinline__ float bf2f(unsigned u16) {
    union { unsigned u; float f; } v; v.u = u16 << 16;
    return v.f;
}
__device__ __forceinline__ unsigned short f2bf(float f) {
    union { float f; unsigned u; } v; v.f = f;
    unsigned u = v.u;
    unsigned r = u + 0x7FFFu + ((u >> 16) & 1u);   // RNE
    return (unsigned short)(r >> 16);
}

// LDS swizzle: tiles are [rows][128 bf16], chunk = 8 bf16 (16B), 16 chunks/row.
// ushort index for (row f, chunk c). Read pattern (f=ct*16+ml, c=kk*4+quad)
// gives every bank exactly 8 accesses per ds_read_b128 -> zero excess conflict.
__device__ __forceinline__ int swz(int f, int c) {
    return f * 128 + ((c ^ (f & 7)) << 3);
}

// 8 consecutive fp32 -> bf16x8 fragment (packed RNE cvt)
__device__ __forceinline__ bf16x8 cvt8(const float* p) {
    float4 x = *(const float4*)p;
    float4 y = *(const float4*)(p + 4);
    union { bf16x8 v; __hip_bfloat162 h[4]; } R;
    R.h[0] = __float22bfloat162_rn(float2{x.x, x.y});
    R.h[1] = __float22bfloat162_rn(float2{x.z, x.w});
    R.h[2] = __float22bfloat162_rn(float2{y.x, y.y});
    R.h[3] = __float22bfloat162_rn(float2{y.z, y.w});
    return R.v;
}

// elementwise relu(a+b) over 8 bf16 pairs (fp32 math), repacked to bf16x8
__device__ __forceinline__ bf16x8 addrelu8(uint4 a, uint4 b) {
    union { uint4 v; unsigned u[4]; } A, B;
    A.v = a; B.v = b;
    union { bf16x8 v; __hip_bfloat162 h[4]; } R;
#pragma unroll
    for (int i = 0; i < 4; ++i) {
        float a0 = bf2f(A.u[i] & 0xFFFFu), a1 = bf2f(A.u[i] >> 16);
        float b0 = bf2f(B.u[i] & 0xFFFFu), b1 = bf2f(B.u[i] >> 16);
        R.h[i] = __float22bfloat162_rn(float2{fmaxf(a0 + b0, 0.f),
                                              fmaxf(a1 + b1, 0.f)});
    }
    return R.v;
}

// ---------------------------------------------------------------------------
// Kernel 0: weight prep (bf16 transposes, plain row-major).
// W1t[j][k] (j in [0,256), k in [0,128)) = W1[k][j] (j<128) | W1[k+128][j-128]
// W2t[n][k] = W2[k][n]
// ---------------------------------------------------------------------------
__global__ void prep_weights(const float* __restrict__ W1,
                             const float* __restrict__ W2,
                             unsigned short* __restrict__ W1t,
                             unsigned short* __restrict__ W2t) {
    int idx = blockIdx.x * 256 + threadIdx.x;
    if (idx < 256 * 128) {
        int j = idx >> 7, k = idx & 127;
        float v = (j < 128) ? W1[k * 128 + j] : W1[(k + 128) * 128 + (j - 128)];
        W1t[idx] = f2bf(v);
    } else {
        int i2 = idx - 256 * 128;
        if (i2 < 128 * 128) {
            int n = i2 >> 7, k = i2 & 127;
            W2t[i2] = f2bf(W2[k * 128 + n]);
        }
    }
}

// ---------------------------------------------------------------------------
// Kernel A: node projection. Block = 256 thr, 128 nodes; wave = 32 nodes.
// W1s (64 KB) staged once; no barriers after that.
// ---------------------------------------------------------------------------
__global__ __launch_bounds__(256, 2) void node_proj(
    const float* __restrict__ h, const unsigned short* __restrict__ W1t,
    const float* __restrict__ b1, unsigned short* __restrict__ P, int nodes) {
    __shared__ unsigned short W1s[256 * 128];

    int t = threadIdx.x;
    int lane = t & 63;
    int w = t >> 6;
    int ml = lane & 15, quad = lane >> 4;

    // stage W1s: thread t -> row t, 16 chunks (swizzled)
    {
        const uint4* src = (const uint4*)(W1t + (size_t)t * 128);
#pragma unroll
        for (int c = 0; c < 16; ++c)
            *(uint4*)(W1s + swz(t, c)) = src[c];
    }

    // prefetch + convert h for this wave's 32 nodes (B-operand: n = ml)
    int nb = blockIdx.x * 128 + w * 32;
    bf16x8 bfrag[2][4];
#pragma unroll
    for (int nt = 0; nt < 2; ++nt) {
        int node = nb + nt * 16 + ml;
        int nodeL = (node < nodes) ? node : (nodes - 1);
        const float* hrow = h + (size_t)nodeL * 128;
#pragma unroll
        for (int kk = 0; kk < 4; ++kk)
            bfrag[nt][kk] = cvt8(hrow + kk * 32 + quad * 8);
    }

    __syncthreads();   // W1s ready

    f32x4 acc[2][16] = {};
#pragma unroll
    for (int kk = 0; kk < 4; ++kk) {
#pragma unroll
        for (int ct = 0; ct < 16; ++ct) {
            bf16x8 afrag = *(const bf16x8*)(W1s + swz(ct * 16 + ml, kk * 4 + quad));
            acc[0][ct] = __builtin_amdgcn_mfma_f32_16x16x32_bf16(
                afrag, bfrag[0][kk], acc[0][ct], 0, 0, 0);
            acc[1][ct] = __builtin_amdgcn_mfma_f32_16x16x32_bf16(
                afrag, bfrag[1][kk], acc[1][ct], 0, 0, 0);
        }
    }

    // epilogue: lane ml owns node; rows (features) = ct*16 + quad*4 + reg
#pragma unroll
    for (int nt = 0; nt < 2; ++nt) {
        int node = nb + nt * 16 + ml;
        if (node < nodes) {
            unsigned short* prow = P + (size_t)node * 256;
#pragma unroll
            for (int ct = 0; ct < 16; ++ct) {
                int fbase = ct * 16 + quad * 4;
                float v0 = acc[nt][ct][0], v1 = acc[nt][ct][1];
                float v2 = acc[nt][ct][2], v3 = acc[nt][ct][3];
                if (fbase >= 128) {
                    float4 bv = *(const float4*)(b1 + (fbase - 128));
                    v0 += bv.x; v1 += bv.y; v2 += bv.z; v3 += bv.w;
                }
                union { uint2 u; __hip_bfloat162 h2[2]; } o;
                o.h2[0] = __float22bfloat162_rn(float2{v0, v1});
                o.h2[1] = __float22bfloat162_rn(float2{v2, v3});
                *(uint2*)(prow + fbase) = o.u;
            }
        }
    }
}

// ---------------------------------------------------------------------------
// Kernel B: per-edge MLP. Block = 256 thr, 64 edges; wave = 16 edges x 2 dir.
// W2s (32 KB) staged once; all 16 P-gathers prefetched before compute.
// ---------------------------------------------------------------------------
__global__ __launch_bounds__(256, 2) void edge_mlp(
    const unsigned short* __restrict__ P, const int* __restrict__ src,
    const int* __restrict__ dst, const unsigned short* __restrict__ W2t,
    const float* __restrict__ b2, const float* __restrict__ W3,
    const float* __restrict__ b3, float* __restrict__ out, int E) {
    __shared__ unsigned short W2s[128 * 128];

    int t = threadIdx.x;
    int lane = t & 63;
    int w = t >> 6;
    int ml = lane & 15, quad = lane >> 4;

    // stage W2s: thread t -> row t>>1, chunks (t&1)*8 .. +7 (swizzled)
    {
        int f = t >> 1, half = t & 1;
        const uint4* s = (const uint4*)(W2t + (size_t)f * 128 + half * 64);
#pragma unroll
        for (int i = 0; i < 8; ++i)
            *(uint4*)(W2s + swz(f, half * 8 + i)) = s[i];
    }

    // prefetch all P gathers for this lane's edge
    int eb = blockIdx.x * 64 + w * 16;
    int e = eb + ml;
    int ec = (e < E) ? e : (E - 1);
    int si = src[ec], di = dst[ec];
    const unsigned short* Ps = P + (size_t)si * 256;
    const unsigned short* Pd = P + (size_t)di * 256;

    uint4 g[4][4];   // [kk][s_lo, s_hi, d_lo, d_hi]
#pragma unroll
    for (int kk = 0; kk < 4; ++kk) {
        int ko = kk * 32 + quad * 8;
        g[kk][0] = *(const uint4*)(Ps + ko);
        g[kk][1] = *(const uint4*)(Ps + 128 + ko);
        g[kk][2] = *(const uint4*)(Pd + ko);
        g[kk][3] = *(const uint4*)(Pd + 128 + ko);
    }

    __syncthreads();   // W2s ready

    f32x4 acc[2][8] = {};
#pragma unroll
    for (int kk = 0; kk < 4; ++kk) {
        bf16x8 afw = addrelu8(g[kk][0], g[kk][3]);   // fwd: relu(P[s,k]+P[d,128+k])
        bf16x8 arv = addrelu8(g[kk][2], g[kk][1]);   // rev: relu(P[d,k]+P[s,128+k])
#pragma unroll
        for (int ct = 0; ct < 8; ++ct) {
            bf16x8 bfrag = *(const bf16x8*)(W2s + swz(ct * 16 + ml, kk * 4 + quad));
            acc[0][ct] = __builtin_amdgcn_mfma_f32_16x16x32_bf16(
                afw, bfrag, acc[0][ct], 0, 0, 0);
            acc[1][ct] = __builtin_amdgcn_mfma_f32_16x16x32_bf16(
                arv, bfrag, acc[1][ct], 0, 0, 0);
        }
    }

    // epilogue: +b2, relu, dot W3 columns, butterfly over 16 feature lanes
    float w30[8], w31[8], b2v[8];
#pragma unroll
    for (int ct = 0; ct < 8; ++ct) {
        int c = ct * 16 + ml;
        w30[ct] = W3[c * 2 + 0];
        w31[ct] = W3[c * 2 + 1];
        b2v[ct] = b2[c];
    }
    float p0[2][4], p1[2][4];
#pragma unroll
    for (int rt = 0; rt < 2; ++rt)
#pragma unroll
        for (int reg = 0; reg < 4; ++reg) { p0[rt][reg] = 0.f; p1[rt][reg] = 0.f; }
#pragma unroll
    for (int rt = 0; rt < 2; ++rt)
#pragma unroll
        for (int ct = 0; ct < 8; ++ct)
#pragma unroll
            for (int reg = 0; reg < 4; ++reg) {
                float h2 = fmaxf(acc[rt][ct][reg] + b2v[ct], 0.f);
                p0[rt][reg] += h2 * w30[ct];
                p1[rt][reg] += h2 * w31[ct];
            }
#pragma unroll
    for (int m = 1; m < 16; m <<= 1) {
#pragma unroll
        for (int rt = 0; rt < 2; ++rt)
#pragma unroll
            for (int reg = 0; reg < 4; ++reg) {
                p0[rt][reg] += __shfl_xor(p0[rt][reg], m);
                p1[rt][reg] += __shfl_xor(p1[rt][reg], m);
            }
    }

    // lane ml==0 writes component 0, ml==1 writes component 1
    if (ml < 2) {
        float bb = 2.f * b3[ml];
#pragma unroll
        for (int reg = 0; reg < 4; ++reg) {
            int ee = eb + quad * 4 + reg;
            if (ee < E) {
                float v = (ml == 0) ? (p0[0][reg] + p0[1][reg])
                                    : (p1[0][reg] + p1[1][reg]);
                out[(size_t)ee * 2 + ml] = v + bb;
            }
        }
    }
}

// ---------------------------------------------------------------------------
extern "C" void kernel_launch(void* const* d_in, const int* in_sizes, int n_in,
                              void* d_out, int out_size, void* d_ws, size_t ws_size,
                              hipStream_t stream) {
    (void)n_in; (void)out_size; (void)ws_size;
    const float* h  = (const float*)d_in[0];
    const int*   sr = (const int*)d_in[1];
    const int*   ds = (const int*)d_in[2];
    const float* W1 = (const float*)d_in[3];
    const float* b1 = (const float*)d_in[4];
    const float* W2 = (const float*)d_in[5];
    const float* b2 = (const float*)d_in[6];
    const float* W3 = (const float*)d_in[7];
    const float* b3 = (const float*)d_in[8];
    float* out = (float*)d_out;

    int nodes = in_sizes[0] / 128;
    int E = in_sizes[1];

    unsigned short* W1t = (unsigned short*)d_ws;          // 256*128
    unsigned short* W2t = W1t + 256 * 128;                // 128*128
    unsigned short* P   = W2t + 128 * 128;                // nodes*256

    prep_weights<<<(256 * 128 + 128 * 128 + 255) / 256, 256, 0, stream>>>(W1, W2, W1t, W2t);

    int ntiles = (nodes + 127) / 128;
    node_proj<<<ntiles, 256, 0, stream>>>(h, W1t, b1, P, nodes);

    int etiles = (E + 63) / 64;
    edge_mlp<<<etiles, 256, 0, stream>>>(P, sr, ds, W2t, b2, W3, b3, out, E);
}

// Round 5
// 245.787 us; speedup vs baseline: 1.4810x; 1.0132x over previous
//
#include <hip/hip_runtime.h>
#include <hip/hip_bf16.h>
#include <stdint.h>

// ---------------------------------------------------------------------------
// BondPoolingLayer: out[e] = MLP(cat(h[src],h[dst])) + MLP(cat(h[dst],h[src]))
// MLP: 256 ->(W1,b1,relu) 128 ->(W2,b2,relu) 128 ->(W3,b3) 2
//
// P[n,0:128] = h[n] @ W1_top ; P[n,128:256] = h[n] @ W1_bot + b1   (bf16)
//   fwd layer1 preact = P[s,0:128] + P[d,128:256]
//   rev layer1 preact = P[d,0:128] + P[s,128:256]
//
// R5 = R3 structure (proven absmax 0.031) + occupancy fixes:
//  - node_proj: 512-thr blocks (64KB W1 LDS -> 2 blocks/CU = 16 waves vs 8),
//    16 nodes/wave (acc[16] = 64 AGPR, total ~130 regs -> reg cap ~15 waves).
//  - edge_mlp: 512-thr blocks over 32KB W2s (staging amortized 2x).
// ---------------------------------------------------------------------------

typedef __attribute__((ext_vector_type(8))) short bf16x8;
typedef __attribute__((ext_vector_type(4))) float f32x4;

__device__ __forceinline__ float bf2f(unsigned u16) {
    union { unsigned u; float f; } v; v.u = u16 << 16;
    return v.f;
}
__device__ __forceinline__ unsigned short f2bf(float f) {
    union { float f; unsigned u; } v; v.f = f;
    unsigned u = v.u;
    unsigned r = u + 0x7FFFu + ((u >> 16) & 1u);   // RNE
    return (unsigned short)(r >> 16);
}

// LDS swizzle: tiles are [rows][128 bf16], chunk = 8 bf16 (16B), 16 chunks/row.
__device__ __forceinline__ int swz(int f, int c) {
    return f * 128 + ((c ^ (f & 7)) << 3);
}

// 8 consecutive fp32 -> bf16x8 fragment (packed RNE cvt)
__device__ __forceinline__ bf16x8 cvt8(const float* p) {
    float4 x = *(const float4*)p;
    float4 y = *(const float4*)(p + 4);
    union { bf16x8 v; __hip_bfloat162 h[4]; } R;
    R.h[0] = __float22bfloat162_rn(float2{x.x, x.y});
    R.h[1] = __float22bfloat162_rn(float2{x.z, x.w});
    R.h[2] = __float22bfloat162_rn(float2{y.x, y.y});
    R.h[3] = __float22bfloat162_rn(float2{y.z, y.w});
    return R.v;
}

// elementwise relu(a+b) over 8 bf16 pairs (fp32 math), repacked to bf16x8
__device__ __forceinline__ bf16x8 addrelu8(uint4 a, uint4 b) {
    union { uint4 v; unsigned u[4]; } A, B;
    A.v = a; B.v = b;
    union { bf16x8 v; __hip_bfloat162 h[4]; } R;
#pragma unroll
    for (int i = 0; i < 4; ++i) {
        float a0 = bf2f(A.u[i] & 0xFFFFu), a1 = bf2f(A.u[i] >> 16);
        float b0 = bf2f(B.u[i] & 0xFFFFu), b1 = bf2f(B.u[i] >> 16);
        R.h[i] = __float22bfloat162_rn(float2{fmaxf(a0 + b0, 0.f),
                                              fmaxf(a1 + b1, 0.f)});
    }
    return R.v;
}

#define MFMA(a, b, c) __builtin_amdgcn_mfma_f32_16x16x32_bf16((a), (b), (c), 0, 0, 0)

// ---------------------------------------------------------------------------
// Kernel 0: weight prep (bf16 transposes, plain row-major).
// W1t[j][k] (j in [0,256), k in [0,128)) = W1[k][j] (j<128) | W1[k+128][j-128]
// W2t[n][k] = W2[k][n]
// ---------------------------------------------------------------------------
__global__ void prep_weights(const float* __restrict__ W1,
                             const float* __restrict__ W2,
                             unsigned short* __restrict__ W1t,
                             unsigned short* __restrict__ W2t) {
    int idx = blockIdx.x * 256 + threadIdx.x;
    if (idx < 256 * 128) {
        int j = idx >> 7, k = idx & 127;
        float v = (j < 128) ? W1[k * 128 + j] : W1[(k + 128) * 128 + (j - 128)];
        W1t[idx] = f2bf(v);
    } else {
        int i2 = idx - 256 * 128;
        if (i2 < 128 * 128) {
            int n = i2 >> 7, k = i2 & 127;
            W2t[i2] = f2bf(W2[k * 128 + n]);
        }
    }
}

// ---------------------------------------------------------------------------
// Kernel A: node projection. Block = 512 thr = 8 waves = 128 nodes.
// Wave = 16 nodes x 256 features (acc[16], 64 AGPR). W1s 64KB staged once.
// ---------------------------------------------------------------------------
__global__ __launch_bounds__(512, 2) void node_proj(
    const float* __restrict__ h, const unsigned short* __restrict__ W1t,
    const float* __restrict__ b1, unsigned short* __restrict__ P, int nodes) {
    __shared__ unsigned short W1s[256 * 128];

    int t = threadIdx.x;
    int lane = t & 63;
    int wv = t >> 6;
    int ml = lane & 15, quad = lane >> 4;

    // stage W1s: thread t -> row t>>1, 8 chunks (swizzled)
    {
        int r = t >> 1, half = t & 1;
        const uint4* src = (const uint4*)(W1t + (size_t)r * 128 + half * 64);
#pragma unroll
        for (int i = 0; i < 8; ++i)
            *(uint4*)(W1s + swz(r, half * 8 + i)) = src[i];
    }

    // prefetch + convert h for this wave's 16 nodes (B-operand: n = ml)
    int node = blockIdx.x * 128 + wv * 16 + ml;
    int nodeL = (node < nodes) ? node : (nodes - 1);
    const float* hrow = h + (size_t)nodeL * 128;
    bf16x8 bfrag[4];
#pragma unroll
    for (int kk = 0; kk < 4; ++kk)
        bfrag[kk] = cvt8(hrow + kk * 32 + quad * 8);

    __syncthreads();   // W1s ready

    f32x4 acc[16] = {};
#pragma unroll
    for (int kk = 0; kk < 4; ++kk) {
#pragma unroll
        for (int ct = 0; ct < 16; ++ct) {
            bf16x8 afrag = *(const bf16x8*)(W1s + swz(ct * 16 + ml, kk * 4 + quad));
            acc[ct] = MFMA(afrag, bfrag[kk], acc[ct]);
        }
    }

    // epilogue: lane ml owns node; rows (features) = ct*16 + quad*4 + reg
    if (node < nodes) {
        unsigned short* prow = P + (size_t)node * 256;
#pragma unroll
        for (int ct = 0; ct < 16; ++ct) {
            int fbase = ct * 16 + quad * 4;
            float v0 = acc[ct][0], v1 = acc[ct][1];
            float v2 = acc[ct][2], v3 = acc[ct][3];
            if (fbase >= 128) {
                float4 bv = *(const float4*)(b1 + (fbase - 128));
                v0 += bv.x; v1 += bv.y; v2 += bv.z; v3 += bv.w;
            }
            union { uint2 u; __hip_bfloat162 h2[2]; } o;
            o.h2[0] = __float22bfloat162_rn(float2{v0, v1});
            o.h2[1] = __float22bfloat162_rn(float2{v2, v3});
            *(uint2*)(prow + fbase) = o.u;
        }
    }
}

// ---------------------------------------------------------------------------
// Kernel B: per-edge MLP. Block = 512 thr = 8 waves = 128 edges.
// Wave = 16 edges x {fwd,rev}. W2s 32KB staged once; P-gathers prefetched.
// ---------------------------------------------------------------------------
__global__ __launch_bounds__(512, 2) void edge_mlp(
    const unsigned short* __restrict__ P, const int* __restrict__ src,
    const int* __restrict__ dst, const unsigned short* __restrict__ W2t,
    const float* __restrict__ b2, const float* __restrict__ W3,
    const float* __restrict__ b3, float* __restrict__ out, int E) {
    __shared__ unsigned short W2s[128 * 128];

    int t = threadIdx.x;
    int lane = t & 63;
    int wv = t >> 6;
    int ml = lane & 15, quad = lane >> 4;

    // stage W2s: thread t -> row t>>2, 4 chunks (swizzled)
    {
        int f = t >> 2, q4 = t & 3;
        const uint4* s = (const uint4*)(W2t + (size_t)f * 128 + q4 * 32);
#pragma unroll
        for (int i = 0; i < 4; ++i)
            *(uint4*)(W2s + swz(f, q4 * 4 + i)) = s[i];
    }

    // prefetch all P gathers for this lane's edge
    int e = blockIdx.x * 128 + wv * 16 + ml;
    int ec = (e < E) ? e : (E - 1);
    int si = src[ec], di = dst[ec];
    const unsigned short* Ps = P + (size_t)si * 256;
    const unsigned short* Pd = P + (size_t)di * 256;

    uint4 g[4][4];   // [kk][s_lo, s_hi, d_lo, d_hi]
#pragma unroll
    for (int kk = 0; kk < 4; ++kk) {
        int ko = kk * 32 + quad * 8;
        g[kk][0] = *(const uint4*)(Ps + ko);
        g[kk][1] = *(const uint4*)(Ps + 128 + ko);
        g[kk][2] = *(const uint4*)(Pd + ko);
        g[kk][3] = *(const uint4*)(Pd + 128 + ko);
    }

    __syncthreads();   // W2s ready

    f32x4 acc[2][8] = {};
#pragma unroll
    for (int kk = 0; kk < 4; ++kk) {
        bf16x8 afw = addrelu8(g[kk][0], g[kk][3]);   // fwd: relu(P[s,k]+P[d,128+k])
        bf16x8 arv = addrelu8(g[kk][2], g[kk][1]);   // rev: relu(P[d,k]+P[s,128+k])
#pragma unroll
        for (int ct = 0; ct < 8; ++ct) {
            bf16x8 bfrag = *(const bf16x8*)(W2s + swz(ct * 16 + ml, kk * 4 + quad));
            acc[0][ct] = MFMA(afw, bfrag, acc[0][ct]);
            acc[1][ct] = MFMA(arv, bfrag, acc[1][ct]);
        }
    }

    // epilogue: +b2, relu, dot W3 columns, butterfly over 16 feature lanes
    float w30[8], w31[8], b2v[8];
#pragma unroll
    for (int ct = 0; ct < 8; ++ct) {
        int c = ct * 16 + ml;
        w30[ct] = W3[c * 2 + 0];
        w31[ct] = W3[c * 2 + 1];
        b2v[ct] = b2[c];
    }
    float p0[2][4], p1[2][4];
#pragma unroll
    for (int rt = 0; rt < 2; ++rt)
#pragma unroll
        for (int reg = 0; reg < 4; ++reg) { p0[rt][reg] = 0.f; p1[rt][reg] = 0.f; }
#pragma unroll
    for (int rt = 0; rt < 2; ++rt)
#pragma unroll
        for (int ct = 0; ct < 8; ++ct)
#pragma unroll
            for (int reg = 0; reg < 4; ++reg) {
                float h2 = fmaxf(acc[rt][ct][reg] + b2v[ct], 0.f);
                p0[rt][reg] += h2 * w30[ct];
                p1[rt][reg] += h2 * w31[ct];
            }
#pragma unroll
    for (int m = 1; m < 16; m <<= 1) {
#pragma unroll
        for (int rt = 0; rt < 2; ++rt)
#pragma unroll
            for (int reg = 0; reg < 4; ++reg) {
                p0[rt][reg] += __shfl_xor(p0[rt][reg], m);
                p1[rt][reg] += __shfl_xor(p1[rt][reg], m);
            }
    }

    // lane ml==0 writes component 0, ml==1 writes component 1
    if (ml < 2) {
        float bb = 2.f * b3[ml];
#pragma unroll
        for (int reg = 0; reg < 4; ++reg) {
            int ee = blockIdx.x * 128 + wv * 16 + quad * 4 + reg;
            if (ee < E) {
                float v = (ml == 0) ? (p0[0][reg] + p0[1][reg])
                                    : (p1[0][reg] + p1[1][reg]);
                out[(size_t)ee * 2 + ml] = v + bb;
            }
        }
    }
}

// ---------------------------------------------------------------------------
extern "C" void kernel_launch(void* const* d_in, const int* in_sizes, int n_in,
                              void* d_out, int out_size, void* d_ws, size_t ws_size,
                              hipStream_t stream) {
    (void)n_in; (void)out_size; (void)ws_size;
    const float* h  = (const float*)d_in[0];
    const int*   sr = (const int*)d_in[1];
    const int*   ds = (const int*)d_in[2];
    const float* W1 = (const float*)d_in[3];
    const float* b1 = (const float*)d_in[4];
    const float* W2 = (const float*)d_in[5];
    const float* b2 = (const float*)d_in[6];
    const float* W3 = (const float*)d_in[7];
    const float* b3 = (const float*)d_in[8];
    float* out = (float*)d_out;

    int nodes = in_sizes[0] / 128;
    int E = in_sizes[1];

    unsigned short* W1t = (unsigned short*)d_ws;          // 256*128
    unsigned short* W2t = W1t + 256 * 128;                // 128*128
    unsigned short* P   = W2t + 128 * 128;                // nodes*256

    prep_weights<<<(256 * 128 + 128 * 128 + 255) / 256, 256, 0, stream>>>(W1, W2, W1t, W2t);

    int ntiles = (nodes + 127) / 128;
    node_proj<<<ntiles, 512, 0, stream>>>(h, W1t, b1, P, nodes);

    int etiles = (E + 127) / 128;
    edge_mlp<<<etiles, 512, 0, stream>>>(P, sr, ds, W2t, b2, W3, b3, out, E);
}